// Round 7
// baseline (375.432 us; speedup 1.0000x reference)
//
#include <hip/hip_runtime.h>
#include <hip/hip_bf16.h>

// ---------------------------------------------------------------------------
// FakeFlexOlmoSparseMlp: top-2 MoE over 8 experts, H=1024, 8192 tokens.
// R11 = R10 with the MODE-0 epilogue stride bug fixed. R10 post-mortem:
// EP_LDSW=136 (128-col stride) was kept while the block widened to 256
// cols -> smem[(r)*136 + col] aliases (r,c>=136)<->(r+1,c-136), corrupt h1,
// absmax 0.83. 256x264 tile (67.6K shorts) exceeds 64K-short LDS, so the
// epilogue now runs in TWO 128-row passes at stride 264 (33.8K shorts).
// K-loop unchanged (untested R10 hypothesis): 256x256 8-phase ring,
// counted vmcnt(4) never draining, setprio around 32-MFMA cluster,
// XCD-swizzled 288-block grid, dense chunk-ordered A via gather.
// ---------------------------------------------------------------------------

#define HD   1024
#define NTOK 8192
#define NEXP 8
#define ZROW 8192     // sentinel: pad slots reference this (virtual) row
#define MAXP 18432    // 16384 pairs + 8*256 max padding = 72 tiles of 256
#define EPW  264      // epilogue LDS row stride (shorts); 528B = 16B-aligned

typedef __attribute__((ext_vector_type(8))) short  vshort8;
typedef __attribute__((ext_vector_type(4))) short  vshort4;
typedef __attribute__((ext_vector_type(4))) float  vfloat4;

typedef __attribute__((address_space(1))) const unsigned gas_uint;
typedef __attribute__((address_space(3))) unsigned       las_uint;

__device__ __forceinline__ void gld16(const void* g, void* l) {
    // async global->LDS, 16B/lane; LDS dest = wave-uniform base + lane*16
    __builtin_amdgcn_global_load_lds((gas_uint*)g, (las_uint*)l, 16, 0, 0);
}

__device__ __forceinline__ short bf16r(float f) {
    union { float f; unsigned u; } a; a.f = f;
    unsigned r = a.u + 0x7FFFu + ((a.u >> 16) & 1u);   // round-to-nearest-even
    return (short)(r >> 16);
}

// --- K1: zero meta, pair_token -> ZROW sentinel ----------------------------
__global__ void init_kernel(int* counts, int* fill, int* pair_token) {
    int i = blockIdx.x * 256 + threadIdx.x;
    if (i < NEXP) { counts[i] = 0; fill[i] = 0; }
    if (i < MAXP) pair_token[i] = ZROW;
}

// --- K2: router fused with residual-copy -----------------------------------
__global__ __launch_bounds__(256) void router_kernel(
    const float* __restrict__ x, const float* __restrict__ rw,
    float* __restrict__ out,
    float* __restrict__ probs_out, int2* __restrict__ tok_top,
    float2* __restrict__ tok_w, int* __restrict__ counts) {
    __shared__ float rws[NEXP * HD];
    __shared__ int hist[NEXP];
    int t = threadIdx.x;
    if (t < NEXP) hist[t] = 0;
    for (int j = 0; j < 8; ++j) {
        int idx = j * 1024 + t * 4;
        *(vfloat4*)(rws + idx) = *(const vfloat4*)(rw + idx);
    }
    __syncthreads();
    int wave = t >> 6, lane = t & 63;
    for (int it = 0; it < 8; ++it) {
        int token = blockIdx.x * 32 + it * 4 + wave;
        const float* xr = x + (size_t)token * HD;
        float part[NEXP];
#pragma unroll
        for (int e = 0; e < NEXP; ++e) part[e] = 0.f;
        for (int j = 0; j < 4; ++j) {
            int off = j * 256 + lane * 4;
            vfloat4 xv = *(const vfloat4*)(xr + off);
            *(vfloat4*)(out + (size_t)token * HD + off) = xv;   // residual init
#pragma unroll
            for (int e = 0; e < NEXP; ++e) {
                vfloat4 wv = *(const vfloat4*)(rws + e * HD + off);
                part[e] += xv.x * wv.x + xv.y * wv.y + xv.z * wv.z + xv.w * wv.w;
            }
        }
#pragma unroll
        for (int e = 0; e < NEXP; ++e)
            for (int off = 32; off; off >>= 1)
                part[e] += __shfl_xor(part[e], off, 64);
        if (lane == 0) {
            float m = part[0];
#pragma unroll
            for (int e = 1; e < NEXP; ++e) m = fmaxf(m, part[e]);
            float p[NEXP], s = 0.f;
#pragma unroll
            for (int e = 0; e < NEXP; ++e) { p[e] = expf(part[e] - m); s += p[e]; }
            float inv = 1.f / s;
#pragma unroll
            for (int e = 0; e < NEXP; ++e) {
                p[e] *= inv;
                probs_out[(size_t)token * NEXP + e] = p[e];
            }
            int i0 = 0;
#pragma unroll
            for (int e = 1; e < NEXP; ++e) if (p[e] > p[i0]) i0 = e;  // ties -> lowest idx
            int i1 = (i0 == 0) ? 1 : 0;
#pragma unroll
            for (int e = 0; e < NEXP; ++e) if (e != i0 && p[e] > p[i1]) i1 = e;
            float s2 = 1.f / (p[i0] + p[i1]);
            tok_top[token] = make_int2(i0, i1);
            tok_w[token]   = make_float2(p[i0] * s2, p[i1] * s2);
            atomicAdd(&hist[i0], 1);
            atomicAdd(&hist[i1], 1);
        }
    }
    __syncthreads();
    if (t < NEXP) atomicAdd(&counts[t], hist[t]);
}

// --- K3: scatter pairs into expert buckets (256-padded offsets) ------------
__global__ __launch_bounds__(256) void scatter_kernel(
    const int2* __restrict__ tok_top, const float2* __restrict__ tok_w,
    const int* __restrict__ counts, int* fill,
    int* __restrict__ pair_token, float* __restrict__ pair_w) {
    __shared__ int lhist[NEXP];
    __shared__ int lbase[NEXP];
    int t = threadIdx.x;
    if (t < NEXP) lhist[t] = 0;
    __syncthreads();
    int offs[NEXP];
    {
        int acc = 0;
#pragma unroll
        for (int f = 0; f < NEXP; ++f) {
            offs[f] = acc;
            acc += (counts[f] + 255) & ~255;
        }
    }
    int token = blockIdx.x * 256 + t;
    int2 ti = tok_top[token];
    float2 tw = tok_w[token];
    int r0 = atomicAdd(&lhist[ti.x], 1);
    int r1 = atomicAdd(&lhist[ti.y], 1);
    __syncthreads();
    if (t < NEXP) lbase[t] = atomicAdd(&fill[t], lhist[t]);
    __syncthreads();
    int s0 = offs[ti.x] + lbase[ti.x] + r0;
    pair_token[s0] = token; pair_w[s0] = tw.x;
    int s1 = offs[ti.y] + lbase[ti.y] + r1;
    pair_token[s1] = token; pair_w[s1] = tw.y;
}

// --- K4: fp32 W1+W2 -> bf16 in MFMA-fragment chunk order -------------------
// Chunk C = ((e*64 + ng)*32 + kc): 64 lanes x 16B; lane l holds
// W[e][ng*16 + (l&15)][kc*32 + (l>>4)*8 .. +7].
__global__ void convw_kernel(const float* __restrict__ W1, const float* __restrict__ W2,
                             short* __restrict__ D1, short* __restrict__ D2) {
    size_t t = (size_t)blockIdx.x * 256 + threadIdx.x;
    const size_t PER = (size_t)NEXP * HD * HD / 8;
    const float* src = W1; short* dst = D1;
    if (t >= PER) { t -= PER; src = W2; dst = D2; }
    size_t C = t >> 6;
    int l  = (int)(t & 63);
    int kc = (int)(C & 31);
    int ng = (int)((C >> 5) & 63);
    int ei = (int)(C >> 11);
    int n = ng * 16 + (l & 15);
    int k = kc * 32 + (l >> 4) * 8;
    const float* s = src + ((size_t)ei * HD + n) * HD + k;
    vfloat4 a = *(const vfloat4*)s;
    vfloat4 b = *(const vfloat4*)(s + 4);
    vshort8 o;
    o[0] = bf16r(a.x); o[1] = bf16r(a.y); o[2] = bf16r(a.z); o[3] = bf16r(a.w);
    o[4] = bf16r(b.x); o[5] = bf16r(b.y); o[6] = bf16r(b.z); o[7] = bf16r(b.w);
    *(vshort8*)(dst + t * 8) = o;
}

// --- K4b: gather pair rows from fp32 x -> bf16 xg in chunk order -----------
__global__ __launch_bounds__(256) void gather_kernel(
    const float* __restrict__ x, const int* __restrict__ pair_token,
    short* __restrict__ xg) {
    int id = blockIdx.x * 256 + threadIdx.x;
    int C = id >> 6, l = id & 63;
    int slot = ((C >> 5) << 4) + (l & 15);
    int k = (C & 31) * 32 + (l >> 4) * 8;
    int tok = pair_token[slot];
    vshort8 o = {0, 0, 0, 0, 0, 0, 0, 0};
    if (tok < ZROW) {
        const float* s = x + (size_t)tok * HD + k;
        vfloat4 a = *(const vfloat4*)s;
        vfloat4 b = *(const vfloat4*)(s + 4);
        o[0] = bf16r(a.x); o[1] = bf16r(a.y); o[2] = bf16r(a.z); o[3] = bf16r(a.w);
        o[4] = bf16r(b.x); o[5] = bf16r(b.y); o[6] = bf16r(b.z); o[7] = bf16r(b.w);
    }
    *(vshort8*)(xg + (size_t)id * 8) = o;
}

// --- K5/K6: 256x256 8-phase grouped GEMM, 8 waves (2x4) of 128x64 ----------
// LDS: ring of 4 kc-slots, slot = A 16 chunks (16KB) + B 16 chunks (16KB).
// Phase P (= kc P): 4 bf + 8 af ds_read_b128 from slot P&3; stage kc P+2
// (wave<4: A row-groups 4w..4w+3; wave>=4: B col-groups 4(w-4)..+3) into
// slot (P+2)&3; setprio(1) 32 MFMA setprio(0); s_waitcnt vmcnt(4) [kc P+1
// landed, kc P+2 still flying -- never drains till tail]; s_barrier.
// MODE 0: epi relu(acc+b1) -> LDS in TWO 128-row passes (128 x EPW=264
// stride, 33.8K shorts/pass) -> chunk-ordered h1.
// MODE 1: epi atomicAdd out += w*(acc+b2), per-row-frag to bound VGPR.
template <int MODE>
__global__ __launch_bounds__(512, 2) void moe_gemm(
    const short* __restrict__ A, const short* __restrict__ Bw,
    const float* __restrict__ bias, const int* __restrict__ pair_token,
    const float* __restrict__ pair_w, const int* __restrict__ counts,
    short* __restrict__ h1sw_out, float* __restrict__ out) {
    __shared__ short smem[65536];   // 128 KB: 4 slots x 16384 shorts

    // XCD swizzle: 288 blocks = 36 x 8 (bijective). Remap so each XCD owns
    // 36 consecutive row-tiles of one column block (B panels L2-resident).
    int lin = blockIdx.y * 72 + blockIdx.x;
    int swz = (lin & 7) * 36 + (lin >> 3);
    int row_t = swz % 72, col_t = swz / 72;

    const int row0 = row_t * 256;
    int e = 0;
    {
        int csum = 0;
#pragma unroll
        for (int f = 0; f < NEXP; ++f) {
            int p = (counts[f] + 255) & ~255;
            if (csum + p <= row0) e = f + 1;
            csum += p;
        }
        if (row0 >= csum) return;       // past padded total
    }

    const int t = threadIdx.x;
    const int wave = t >> 6, lane = t & 63;
    const int wm = wave >> 2, wn = wave & 3;     // wave tile: rows wm*128, cols wn*64
    const int quad = lane >> 4, l16 = lane & 15;
    const int colb = col_t * 256;

    // stage streams: 4 chunks/wave/phase; kc advance = +1024 B
    const char *sp0, *sp1, *sp2, *sp3;
    int dof0, dof1, dof2, dof3;
    if (wave < 4) {
        int rgb = wave * 4;
        const char* ab = (const char*)A + ((size_t)(row0 >> 4) + rgb) * 32768 + lane * 16;
        sp0 = ab; sp1 = ab + 32768; sp2 = ab + 65536; sp3 = ab + 98304;
        dof0 = (rgb + 0) * 512; dof1 = (rgb + 1) * 512;
        dof2 = (rgb + 2) * 512; dof3 = (rgb + 3) * 512;
    } else {
        int cgb = (wave - 4) * 4;
        const char* bb = (const char*)Bw +
            ((size_t)e * 64 + (colb >> 4) + cgb) * 32768 + lane * 16;
        sp0 = bb; sp1 = bb + 32768; sp2 = bb + 65536; sp3 = bb + 98304;
        dof0 = 8192 + (cgb + 0) * 512; dof1 = 8192 + (cgb + 1) * 512;
        dof2 = 8192 + (cgb + 2) * 512; dof3 = 8192 + (cgb + 3) * 512;
    }

    vfloat4 acc[8][4];
#pragma unroll
    for (int i = 0; i < 8; ++i)
#pragma unroll
        for (int j = 0; j < 4; ++j)
            acc[i][j] = (vfloat4){0.f, 0.f, 0.f, 0.f};

#define STG(P)                                                                \
    {                                                                         \
        short* d_ = smem + ((P) & 3) * 16384;                                 \
        gld16(sp0 + (size_t)(P) * 1024, d_ + dof0);                           \
        gld16(sp1 + (size_t)(P) * 1024, d_ + dof1);                           \
        gld16(sp2 + (size_t)(P) * 1024, d_ + dof2);                           \
        gld16(sp3 + (size_t)(P) * 1024, d_ + dof3);                           \
    }

#define PHASE(P)                                                              \
    {                                                                         \
        const short* sl_ = smem + ((P) & 3) * 16384;                          \
        vshort8 bf[4], af[8];                                                 \
        _Pragma("unroll")                                                     \
        for (int j = 0; j < 4; ++j)                                           \
            bf[j] = *(const vshort8*)(sl_ + 8192 + (wn * 4 + j) * 512 + lane * 8); \
        _Pragma("unroll")                                                     \
        for (int i = 0; i < 8; ++i)                                           \
            af[i] = *(const vshort8*)(sl_ + (wm * 8 + i) * 512 + lane * 8);   \
        if ((P) < 30) STG((P) + 2)                                            \
        __builtin_amdgcn_s_setprio(1);                                        \
        _Pragma("unroll")                                                     \
        for (int i = 0; i < 8; ++i)                                           \
            _Pragma("unroll")                                                 \
            for (int j = 0; j < 4; ++j)                                       \
                acc[i][j] = __builtin_amdgcn_mfma_f32_16x16x32_bf16(          \
                    af[i], bf[j], acc[i][j], 0, 0, 0);                        \
        __builtin_amdgcn_s_setprio(0);                                        \
        if ((P) < 30) { asm volatile("s_waitcnt vmcnt(4)" ::: "memory"); }    \
        else          { asm volatile("s_waitcnt vmcnt(0)" ::: "memory"); }    \
        __builtin_amdgcn_s_barrier();                                         \
    }

    // prologue: kc 0,1 staged; wait kc0 landed (kc1 still flying)
    STG(0)
    STG(1)
    asm volatile("s_waitcnt vmcnt(4)" ::: "memory");
    __builtin_amdgcn_s_barrier();

#pragma unroll
    for (int P = 0; P < 30; ++P) PHASE(P)
    PHASE(30)
    PHASE(31)
#undef PHASE
#undef STG

    if (MODE == 0) {
        // epilogue: relu(acc+b1) -> bf16 LDS in TWO 128-row passes
        // (128 x EPW stride = 33.8K shorts, fits the 64K-short ring) ->
        // chunk-ordered h1. Pass p handles rows [p*128, p*128+128).
#pragma unroll
        for (int p = 0; p < 2; ++p) {
            if (wm == p) {                   // 4 waves own this 128-row half
#pragma unroll
                for (int j = 0; j < 4; ++j) {
                    int col = wn * 64 + j * 16 + l16;
                    float bv = bias[e * HD + colb + col];
#pragma unroll
                    for (int i = 0; i < 8; ++i) {
                        int rl = i * 16 + quad * 4;      // local row within half
#pragma unroll
                        for (int reg = 0; reg < 4; ++reg) {
                            float v = acc[i][j][reg] + bv;
                            v = v > 0.f ? v : 0.f;
                            smem[(rl + reg) * EPW + col] = bf16r(v);
                        }
                    }
                }
            }
            __syncthreads();
            // 64 chunks this half (8 rg x 8 kc); wave w: rg = w, kc 0..7
#pragma unroll
            for (int kc = 0; kc < 8; ++kc) {
                vshort8 v = *(const vshort8*)(smem + (wave * 16 + l16) * EPW + kc * 32 + quad * 8);
                size_t chunk = ((size_t)(row0 >> 4) + p * 8 + wave) * 32 + (colb >> 5) + kc;
                *(vshort8*)(h1sw_out + chunk * 512 + lane * 8) = v;
            }
            if (p == 0) __syncthreads();     // half-0 reads done before half-1 writes
        }
    } else {
        // epilogue: out += w * (acc + b2); per-row-frag to bound VGPR
#pragma unroll
        for (int i = 0; i < 8; ++i) {
            int rbase = row0 + wm * 128 + i * 16 + quad * 4;
            int   tok0 = pair_token[rbase + 0], tok1 = pair_token[rbase + 1];
            int   tok2 = pair_token[rbase + 2], tok3 = pair_token[rbase + 3];
            float wv0 = pair_w[rbase + 0], wv1 = pair_w[rbase + 1];
            float wv2 = pair_w[rbase + 2], wv3 = pair_w[rbase + 3];
#pragma unroll
            for (int j = 0; j < 4; ++j) {
                int col = colb + wn * 64 + j * 16 + l16;
                float bv = bias[e * HD + col];
                if (tok0 < ZROW) atomicAdd(out + (size_t)tok0 * HD + col, wv0 * (acc[i][j][0] + bv));
                if (tok1 < ZROW) atomicAdd(out + (size_t)tok1 * HD + col, wv1 * (acc[i][j][1] + bv));
                if (tok2 < ZROW) atomicAdd(out + (size_t)tok2 * HD + col, wv2 * (acc[i][j][2] + bv));
                if (tok3 < ZROW) atomicAdd(out + (size_t)tok3 * HD + col, wv3 * (acc[i][j][3] + bv));
            }
        }
    }
}

extern "C" void kernel_launch(void* const* d_in, const int* in_sizes, int n_in,
                              void* d_out, int out_size, void* d_ws, size_t ws_size,
                              hipStream_t stream) {
    const float* x  = (const float*)d_in[0];
    const float* rw = (const float*)d_in[1];
    const float* W1 = (const float*)d_in[2];
    const float* b1 = (const float*)d_in[3];
    const float* W2 = (const float*)d_in[4];
    const float* b2 = (const float*)d_in[5];
    float* out   = (float*)d_out;                // [8192,1024] residual+moe
    float* probs = out + (size_t)NTOK * HD;      // [8192,8]

    char* ws = (char*)d_ws;
    short* xg = (short*)ws;            ws += (size_t)MAXP * HD * 2;
    short* h1 = (short*)ws;            ws += (size_t)MAXP * HD * 2;
    int*   pair_token = (int*)ws;      ws += MAXP * 4;
    float* pair_w     = (float*)ws;    ws += MAXP * 4;
    int*   counts = (int*)ws;          ws += 256;
    int*   fill   = (int*)ws;          ws += 256;
    int2*   tok_top = (int2*)ws;       ws += NTOK * 8;
    float2* tok_w   = (float2*)ws;     ws += NTOK * 8;
    short* w1sw = (short*)ws;          ws += (size_t)NEXP * HD * HD * 2;
    short* w2sw = (short*)ws;          ws += (size_t)NEXP * HD * HD * 2;
    (void)ws_size;

    init_kernel<<<MAXP / 256, 256, 0, stream>>>(counts, fill, pair_token);
    router_kernel<<<NTOK / 32, 256, 0, stream>>>(x, rw, out, probs,
                                                 tok_top, tok_w, counts);
    scatter_kernel<<<NTOK / 256, 256, 0, stream>>>(tok_top, tok_w, counts, fill,
                                                   pair_token, pair_w);
    int cg = (int)(2 * ((size_t)NEXP * HD * HD / 8) / 256);   // 8192 blocks
    convw_kernel<<<cg, 256, 0, stream>>>(W1, W2, w1sw, w2sw);
    gather_kernel<<<(MAXP * (HD / 8)) / 256, 256, 0, stream>>>(x, pair_token, xg);
    dim3 gg(72, 4);                    // 288 blocks; past-padded-total exit
    moe_gemm<0><<<gg, 512, 0, stream>>>(xg, w1sw, b1, pair_token, pair_w, counts, h1, nullptr);
    moe_gemm<1><<<gg, 512, 0, stream>>>(h1, w2sw, b2, pair_token, pair_w, counts, nullptr, out);
}

// Round 10
// 302.291 us; speedup vs baseline: 1.2420x; 1.2420x over previous
//
#include <hip/hip_runtime.h>
#include <hip/hip_bf16.h>

// ---------------------------------------------------------------------------
// FakeFlexOlmoSparseMlp: top-2 MoE over 8 experts, H=1024, 8192 tokens.
// R14 = R13 with hipMemsetAsync replaced by a one-block zero_kernel (the
// only novel host API in R13; container failed twice at infra level, so we
// return to the launch-only pattern that passed 8 rounds). Unchanged and
// still under test: (a) prep fusion (router | convw | init in one dispatch;
// counts/fill zeroed by the PRIOR zero dispatch -> no in-dispatch race,
// G16); (b) R5's proven GEMM loop (96us) + bijective XCD remap
// (col_t = bx&7 == hw XCD id -> each XCD reads one 128-col B slice of all
// experts, 2MB, L2-resident).
// ---------------------------------------------------------------------------

#define HD   1024
#define NTOK 8192
#define NEXP 8
#define BM   128
#define BN   128
#define BK   64
#define ZROW 8192     // sentinel row in x_bf16 filled with zeros (pad slots)
#define MAXP 17408    // 16384 pairs + 8*128 max padding = 136 tiles of 128
#define EP_LDSW 136   // epilogue LDS row stride (shorts); 272B = 16B-aligned

typedef __attribute__((ext_vector_type(8))) short  vshort8;
typedef __attribute__((ext_vector_type(4))) short  vshort4;
typedef __attribute__((ext_vector_type(4))) float  vfloat4;

typedef __attribute__((address_space(1))) const unsigned gas_uint;
typedef __attribute__((address_space(3))) unsigned       las_uint;

__device__ __forceinline__ void gld16(const void* g, void* l) {
    // async global->LDS, 16B/lane; LDS dest = wave-uniform base + lane*16
    __builtin_amdgcn_global_load_lds((gas_uint*)g, (las_uint*)l, 16, 0, 0);
}

__device__ __forceinline__ short bf16r(float f) {
    union { float f; unsigned u; } a; a.f = f;
    unsigned r = a.u + 0x7FFFu + ((a.u >> 16) & 1u);   // round-to-nearest-even
    return (short)(r >> 16);
}

// --- K0: zero counts+fill (single block; runs BEFORE prep, stream-ordered) -
__global__ void zero_kernel(int* counts, int* fill) {
    int t = threadIdx.x;
    if (t < NEXP) { counts[t] = 0; fill[t] = 0; }
}

// --- K1 (fused prep): router [0,256) | convw [256,8448) | init [8448,8516) -
// counts/fill zeroed by zero_kernel BEFORE this dispatch; init section must
// NOT touch them (no inter-block ordering within a dispatch, G16).
__global__ __launch_bounds__(256) void prep_kernel(
    const float* __restrict__ x, const float* __restrict__ rw,
    float* __restrict__ out, short* __restrict__ xb,
    float* __restrict__ probs_out, int2* __restrict__ tok_top,
    float2* __restrict__ tok_w, int* __restrict__ counts,
    int* __restrict__ pair_token,
    const float* __restrict__ W1, const float* __restrict__ W2,
    short* __restrict__ D1, short* __restrict__ D2) {
    __shared__ float rws[NEXP * HD];
    __shared__ int hist[NEXP];
    const int blk = blockIdx.x;
    const int t = threadIdx.x;

    if (blk < 256) {
        // ---- router fused with residual-copy + bf16 cast (R5 verbatim) ----
        if (t < NEXP) hist[t] = 0;
        for (int j = 0; j < 8; ++j) {
            int idx = j * 1024 + t * 4;
            *(vfloat4*)(rws + idx) = *(const vfloat4*)(rw + idx);
        }
        __syncthreads();
        int wave = t >> 6, lane = t & 63;
        for (int it = 0; it < 8; ++it) {
            int token = blk * 32 + it * 4 + wave;
            const float* xr = x + (size_t)token * HD;
            float part[NEXP];
#pragma unroll
            for (int e = 0; e < NEXP; ++e) part[e] = 0.f;
            for (int j = 0; j < 4; ++j) {
                int off = j * 256 + lane * 4;
                vfloat4 xv = *(const vfloat4*)(xr + off);
                *(vfloat4*)(out + (size_t)token * HD + off) = xv;   // residual init
                vshort4 bq;
                bq.x = bf16r(xv.x); bq.y = bf16r(xv.y); bq.z = bf16r(xv.z); bq.w = bf16r(xv.w);
                *(vshort4*)(xb + (size_t)token * HD + off) = bq;
#pragma unroll
                for (int e = 0; e < NEXP; ++e) {
                    vfloat4 wv = *(const vfloat4*)(rws + e * HD + off);
                    part[e] += xv.x * wv.x + xv.y * wv.y + xv.z * wv.z + xv.w * wv.w;
                }
            }
#pragma unroll
            for (int e = 0; e < NEXP; ++e)
                for (int off = 32; off; off >>= 1)
                    part[e] += __shfl_xor(part[e], off, 64);
            if (lane == 0) {
                float m = part[0];
#pragma unroll
                for (int e = 1; e < NEXP; ++e) m = fmaxf(m, part[e]);
                float p[NEXP], s = 0.f;
#pragma unroll
                for (int e = 0; e < NEXP; ++e) { p[e] = expf(part[e] - m); s += p[e]; }
                float inv = 1.f / s;
#pragma unroll
                for (int e = 0; e < NEXP; ++e) {
                    p[e] *= inv;
                    probs_out[(size_t)token * NEXP + e] = p[e];
                }
                int i0 = 0;
#pragma unroll
                for (int e = 1; e < NEXP; ++e) if (p[e] > p[i0]) i0 = e;  // ties -> lowest
                int i1 = (i0 == 0) ? 1 : 0;
#pragma unroll
                for (int e = 0; e < NEXP; ++e) if (e != i0 && p[e] > p[i1]) i1 = e;
                float s2 = 1.f / (p[i0] + p[i1]);
                tok_top[token] = make_int2(i0, i1);
                tok_w[token]   = make_float2(p[i0] * s2, p[i1] * s2);
                atomicAdd(&hist[i0], 1);
                atomicAdd(&hist[i1], 1);
            }
        }
        __syncthreads();
        if (t < NEXP) atomicAdd(&counts[t], hist[t]);
    } else if (blk < 8448) {
        // ---- convw: fp32 W1+W2 -> bf16 in MFMA-fragment chunk order -------
        // Chunk C = ((e*64 + ng)*32 + kc): lane l holds
        // W[e][ng*16 + (l&15)][kc*32 + (l>>4)*8 .. +7].
        size_t tt = (size_t)(blk - 256) * 256 + t;
        const size_t PER = (size_t)NEXP * HD * HD / 8;
        const float* src = W1; short* dst = D1;
        if (tt >= PER) { tt -= PER; src = W2; dst = D2; }
        size_t C = tt >> 6;
        int l  = (int)(tt & 63);
        int kc = (int)(C & 31);
        int ng = (int)((C >> 5) & 63);
        int ei = (int)(C >> 11);
        int n = ng * 16 + (l & 15);
        int k = kc * 32 + (l >> 4) * 8;
        const float* s = src + ((size_t)ei * HD + n) * HD + k;
        vfloat4 a = *(const vfloat4*)s;
        vfloat4 b = *(const vfloat4*)(s + 4);
        vshort8 o;
        o[0] = bf16r(a.x); o[1] = bf16r(a.y); o[2] = bf16r(a.z); o[3] = bf16r(a.w);
        o[4] = bf16r(b.x); o[5] = bf16r(b.y); o[6] = bf16r(b.z); o[7] = bf16r(b.w);
        *(vshort8*)(dst + tt * 8) = o;
    } else {
        // ---- init: pair_token -> ZROW sentinel, zero ZROW row (ONLY) ------
        int i = (blk - 8448) * 256 + t;
        if (i < MAXP) pair_token[i] = ZROW;
        if (i < HD / 8) {
            vshort8 z = {0, 0, 0, 0, 0, 0, 0, 0};
            *(vshort8*)(xb + (size_t)ZROW * HD + i * 8) = z;
        }
    }
}

// --- K2: scatter pairs into expert buckets (inline offsets from counts) ----
__global__ __launch_bounds__(256) void scatter_kernel(
    const int2* __restrict__ tok_top, const float2* __restrict__ tok_w,
    const int* __restrict__ counts, int* fill,
    int* __restrict__ pair_token, float* __restrict__ pair_w) {
    __shared__ int lhist[NEXP];
    __shared__ int lbase[NEXP];
    int t = threadIdx.x;
    if (t < NEXP) lhist[t] = 0;
    __syncthreads();
    int offs[NEXP];
    {
        int acc = 0;
#pragma unroll
        for (int f = 0; f < NEXP; ++f) {
            offs[f] = acc;
            acc += (counts[f] + 127) & ~127;
        }
    }
    int token = blockIdx.x * 256 + t;
    int2 ti = tok_top[token];
    float2 tw = tok_w[token];
    int r0 = atomicAdd(&lhist[ti.x], 1);
    int r1 = atomicAdd(&lhist[ti.y], 1);
    __syncthreads();
    if (t < NEXP) lbase[t] = atomicAdd(&fill[t], lhist[t]);
    __syncthreads();
    int s0 = offs[ti.x] + lbase[ti.x] + r0;
    pair_token[s0] = token; pair_w[s0] = tw.x;
    int s1 = offs[ti.y] + lbase[ti.y] + r1;
    pair_token[s1] = token; pair_w[s1] = tw.y;
}

// --- K3/K4: grouped NT-GEMM (R5 verbatim) + bijective XCD remap ------------
// 136x8 grid; hw linear id = by*136+bx, 136%8==0 -> XCD = bx&7. Remap
// col_t = bx&7, row_t = by*17 + (bx>>3): each XCD reads ONE 128-col slice
// of all 8 experts' B (2MB, L2-resident); A/h1 rows L3-served.
// 8 waves (2x4) of 64x32; LDS 64KB dbuf; per k-step: STAGE next (2 gld_lds/
// wave), counted vmcnt(4), s_barrier, 12 ds_read_b128 + 16 MFMA, s_barrier.
// MODE 0: A rows via pair_token; epi relu(acc+b1)->LDS->chunk-ordered h1.
// MODE 1: A = chunk-ordered h1; epi atomicAdd out += w*(acc+b2).
template <int MODE>
__global__ __launch_bounds__(512, 4) void moe_gemm(
    const short* __restrict__ A, const short* __restrict__ Bw,
    const float* __restrict__ bias, const int* __restrict__ pair_token,
    const float* __restrict__ pair_w, const int* __restrict__ counts,
    short* __restrict__ h1sw_out, float* __restrict__ out) {
    __shared__ short smem[32768];   // 64 KB: A dbuf [0..16383], B dbuf [16384..32767]

    const int bx = blockIdx.x, by = blockIdx.y;
    const int row_t = by * 17 + (bx >> 3);   // bijective: 136 = 8*17
    const int col_t = bx & 7;                // == hw_lin%8 == XCD id

    const int row0 = row_t * BM;
    // inline padded prefix over counts -> expert id + total
    int e = 0;
    {
        int csum = 0;
#pragma unroll
        for (int f = 0; f < NEXP; ++f) {
            int p = (counts[f] + 127) & ~127;
            if (csum + p <= row0) e = f + 1;
            csum += p;
        }
        if (row0 >= csum) return;       // past padded total
    }

    const int t = threadIdx.x;
    const int wave = t >> 6, lane = t & 63;
    const int wm = wave >> 2, wn = wave & 3;
    const int quad = lane >> 4, l16 = lane & 15;
    const int colb = col_t * BN;

    // per-lane global source pointers (at k0 = 0)
    const char* agp;
    if (MODE == 0) {
        int tok = pair_token[row0 + wave * 16 + l16];
        agp = (const char*)A + (size_t)tok * (HD * 2) + quad * 16;
    } else {
        agp = (const char*)A + (((size_t)(row0 >> 4) + wave) * 32) * 1024 + lane * 16;
    }
    const char* bgp = (const char*)Bw +
        (((size_t)e * 64 + (colb >> 4) + wave) * 32) * 1024 + lane * 16;

    vfloat4 acc[4][2];
#pragma unroll
    for (int i = 0; i < 4; ++i)
#pragma unroll
        for (int j = 0; j < 2; ++j)
            acc[i][j] = (vfloat4){0.f, 0.f, 0.f, 0.f};

#define STAGE(bsel, kk0)                                                      \
    {                                                                         \
        const int kc_ = (kk0) >> 5;                                           \
        short* sa_ = smem + (bsel) * 8192;                                    \
        short* sb_ = smem + 16384 + (bsel) * 8192;                            \
        _Pragma("unroll")                                                     \
        for (int s = 0; s < 2; ++s) {                                         \
            const char* ga_ = (MODE == 0)                                     \
                ? (agp + (size_t)(kk0) * 2 + s * 64)                          \
                : (agp + (size_t)(kc_ + s) * 1024);                           \
            gld16(ga_, sa_ + (wave * 2 + s) * 512);                           \
            gld16(bgp + (size_t)(kc_ + s) * 1024, sb_ + (wave * 2 + s) * 512);\
        }                                                                     \
    }

    STAGE(0, 0)                              // prologue: 4 loads in flight
    int cur = 0;
    for (int kt = 0; kt < HD / BK; ++kt) {
        if (kt < HD / BK - 1) {
            STAGE(cur ^ 1, (kt + 1) * BK)    // issue next tile: 8 outstanding
            asm volatile("s_waitcnt vmcnt(4)" ::: "memory");  // step-kt loads landed
        } else {
            asm volatile("s_waitcnt vmcnt(0)" ::: "memory");  // drain last tile
        }
        __builtin_amdgcn_s_barrier();        // all waves' tile kt in LDS
        asm volatile("" ::: "memory");
        const short* sa = smem + cur * 8192;
        const short* sb = smem + 16384 + cur * 8192;
#pragma unroll
        for (int s = 0; s < 2; ++s) {
            vshort8 af[4], bfr[2];
#pragma unroll
            for (int i = 0; i < 4; ++i)
                af[i] = *(const vshort8*)(sa + ((wm * 4 + i) * 2 + s) * 512 + lane * 8);
#pragma unroll
            for (int j = 0; j < 2; ++j)
                bfr[j] = *(const vshort8*)(sb + ((wn * 2 + j) * 2 + s) * 512 + lane * 8);
#pragma unroll
            for (int i = 0; i < 4; ++i)
#pragma unroll
                for (int j = 0; j < 2; ++j)
                    acc[i][j] = __builtin_amdgcn_mfma_f32_16x16x32_bf16(af[i], bfr[j], acc[i][j], 0, 0, 0);
        }
        asm volatile("" ::: "memory");
        __builtin_amdgcn_s_barrier();        // reads of buf[cur] done before restage
        cur ^= 1;
    }
#undef STAGE

    if (MODE == 0) {
        // epilogue: relu(acc+b1) -> bf16 LDS tile -> chunk-ordered h1sw
        __syncthreads();
#pragma unroll
        for (int j = 0; j < 2; ++j) {
            int col = wn * 32 + j * 16 + l16;
            float bv = bias[e * HD + colb + col];
#pragma unroll
            for (int i = 0; i < 4; ++i) {
                int rl = wm * 64 + i * 16 + quad * 4;
#pragma unroll
                for (int reg = 0; reg < 4; ++reg) {
                    float v = acc[i][j][reg] + bv;
                    v = v > 0.f ? v : 0.f;
                    smem[(rl + reg) * EP_LDSW + col] = bf16r(v);
                }
            }
        }
        __syncthreads();
        int lrow = wave * 16 + l16;
#pragma unroll
        for (int kk = 0; kk < 4; ++kk) {
            vshort8 v = *(const vshort8*)(smem + lrow * EP_LDSW + kk * 32 + quad * 8);
            size_t chunk = ((size_t)(row0 >> 4) + wave) * 32 + (colb >> 5) + kk;
            *(vshort8*)(h1sw_out + chunk * 512 + lane * 8) = v;
        }
    } else {
        int tok[4][4]; float wv[4][4];
#pragma unroll
        for (int i = 0; i < 4; ++i)
#pragma unroll
            for (int reg = 0; reg < 4; ++reg) {
                int r = row0 + wm * 64 + i * 16 + quad * 4 + reg;
                tok[i][reg] = pair_token[r];
                wv[i][reg] = pair_w[r];
            }
#pragma unroll
        for (int j = 0; j < 2; ++j) {
            int col = colb + wn * 32 + j * 16 + l16;
            float bv = bias[e * HD + col];
#pragma unroll
            for (int i = 0; i < 4; ++i)
#pragma unroll
                for (int reg = 0; reg < 4; ++reg)
                    if (tok[i][reg] < ZROW)
                        atomicAdd(out + (size_t)tok[i][reg] * HD + col,
                                  wv[i][reg] * (acc[i][j][reg] + bv));
        }
    }
}

extern "C" void kernel_launch(void* const* d_in, const int* in_sizes, int n_in,
                              void* d_out, int out_size, void* d_ws, size_t ws_size,
                              hipStream_t stream) {
    const float* x  = (const float*)d_in[0];
    const float* rw = (const float*)d_in[1];
    const float* W1 = (const float*)d_in[2];
    const float* b1 = (const float*)d_in[3];
    const float* W2 = (const float*)d_in[4];
    const float* b2 = (const float*)d_in[5];
    float* out   = (float*)d_out;                // [8192,1024] residual+moe
    float* probs = out + (size_t)NTOK * HD;      // [8192,8]

    char* ws = (char*)d_ws;
    short* xb = (short*)ws;            ws += (size_t)(NTOK + 1) * HD * 2;
    short* h1 = (short*)ws;            ws += (size_t)MAXP * HD * 2;
    int*   pair_token = (int*)ws;      ws += MAXP * 4;
    float* pair_w     = (float*)ws;    ws += MAXP * 4;
    int*   counts = (int*)ws;          ws += 256;
    int*   fill   = (int*)ws;          ws += 256;
    int2*   tok_top = (int2*)ws;       ws += NTOK * 8;
    float2* tok_w   = (float2*)ws;     ws += NTOK * 8;
    short* w1sw = (short*)ws;          ws += (size_t)NEXP * HD * HD * 2;
    short* w2sw = (short*)ws;          ws += (size_t)NEXP * HD * HD * 2;
    (void)ws_size;

    // zero counts/fill in a prior dispatch (stream-ordered; launch-only API)
    zero_kernel<<<1, 256, 0, stream>>>(counts, fill);
    // prep: router [0,256) | convw [256,8448) | init [8448,8516)
    prep_kernel<<<8516, 256, 0, stream>>>(x, rw, out, xb, probs, tok_top, tok_w,
                                          counts, pair_token,
                                          W1, W2, w1sw, w2sw);
    scatter_kernel<<<NTOK / 256, 256, 0, stream>>>(tok_top, tok_w, counts, fill,
                                                   pair_token, pair_w);
    dim3 gg(136, 8);                   // XCD-remapped inside; past-total exit
    moe_gemm<0><<<gg, 512, 0, stream>>>(xb, w1sw, b1, pair_token, pair_w, counts, h1, nullptr);
    moe_gemm<1><<<gg, 512, 0, stream>>>(h1, w2sw, b2, pair_token, pair_w, counts, nullptr, out);
}

// Round 12
// 300.570 us; speedup vs baseline: 1.2491x; 1.0057x over previous
//
#include <hip/hip_runtime.h>
#include <hip/hip_bf16.h>

// ---------------------------------------------------------------------------
// FakeFlexOlmoSparseMlp: top-2 MoE over 8 experts, H=1024, 8192 tokens.
// R16 = R15 with the scatter prefix-granularity bug fixed. R15 post-mortem:
// hist_arr rows are ROUTER blocks (32 tokens each, 256 rows); scatter
// blocks own 256 tokens (= 8 router blocks). The block-prefix predicate
// used (t < b) instead of (t < b*8) -> all blocks except 0 scattered to
// wrong slots -> absmax 0.996. One-predicate fix; rank-within-block via
// LDS atomics is consistent with the 8-router-block prefix.
// Unchanged (measured-best): prep fusion (+9us), R5 GEMM loop + natural
// block mapping (96us/GEMM, 302us total in R14), atomic-free scatter path.
// ---------------------------------------------------------------------------

#define HD   1024
#define NTOK 8192
#define NEXP 8
#define BM   128
#define BN   128
#define BK   64
#define ZROW 8192     // sentinel row in x_bf16 filled with zeros (pad slots)
#define MAXP 17408    // 16384 pairs + 8*128 max padding = 136 tiles of 128
#define EP_LDSW 136   // epilogue LDS row stride (shorts); 272B = 16B-aligned

typedef __attribute__((ext_vector_type(8))) short  vshort8;
typedef __attribute__((ext_vector_type(4))) short  vshort4;
typedef __attribute__((ext_vector_type(4))) float  vfloat4;

typedef __attribute__((address_space(1))) const unsigned gas_uint;
typedef __attribute__((address_space(3))) unsigned       las_uint;

__device__ __forceinline__ void gld16(const void* g, void* l) {
    // async global->LDS, 16B/lane; LDS dest = wave-uniform base + lane*16
    __builtin_amdgcn_global_load_lds((gas_uint*)g, (las_uint*)l, 16, 0, 0);
}

__device__ __forceinline__ short bf16r(float f) {
    union { float f; unsigned u; } a; a.f = f;
    unsigned r = a.u + 0x7FFFu + ((a.u >> 16) & 1u);   // round-to-nearest-even
    return (short)(r >> 16);
}

// --- K1 (fused prep): router [0,256) | convw [256,8448) | init [8448,8516) -
// Router writes per-block histograms to hist_arr (NON-atomic, no pre-zeroed
// global state) -> no in-dispatch ordering hazards at all (G16-clean).
__global__ __launch_bounds__(256) void prep_kernel(
    const float* __restrict__ x, const float* __restrict__ rw,
    float* __restrict__ out, short* __restrict__ xb,
    float* __restrict__ probs_out, int2* __restrict__ tok_top,
    float2* __restrict__ tok_w, int* __restrict__ hist_arr,
    int* __restrict__ pair_token,
    const float* __restrict__ W1, const float* __restrict__ W2,
    short* __restrict__ D1, short* __restrict__ D2) {
    __shared__ float rws[NEXP * HD];
    __shared__ int hist[NEXP];
    const int blk = blockIdx.x;
    const int t = threadIdx.x;

    if (blk < 256) {
        // ---- router fused with residual-copy + bf16 cast ------------------
        if (t < NEXP) hist[t] = 0;
        for (int j = 0; j < 8; ++j) {
            int idx = j * 1024 + t * 4;
            *(vfloat4*)(rws + idx) = *(const vfloat4*)(rw + idx);
        }
        __syncthreads();
        int wave = t >> 6, lane = t & 63;
        for (int it = 0; it < 8; ++it) {
            int token = blk * 32 + it * 4 + wave;
            const float* xr = x + (size_t)token * HD;
            float part[NEXP];
#pragma unroll
            for (int e = 0; e < NEXP; ++e) part[e] = 0.f;
            for (int j = 0; j < 4; ++j) {
                int off = j * 256 + lane * 4;
                vfloat4 xv = *(const vfloat4*)(xr + off);
                *(vfloat4*)(out + (size_t)token * HD + off) = xv;   // residual init
                vshort4 bq;
                bq.x = bf16r(xv.x); bq.y = bf16r(xv.y); bq.z = bf16r(xv.z); bq.w = bf16r(xv.w);
                *(vshort4*)(xb + (size_t)token * HD + off) = bq;
#pragma unroll
                for (int e = 0; e < NEXP; ++e) {
                    vfloat4 wv = *(const vfloat4*)(rws + e * HD + off);
                    part[e] += xv.x * wv.x + xv.y * wv.y + xv.z * wv.z + xv.w * wv.w;
                }
            }
#pragma unroll
            for (int e = 0; e < NEXP; ++e)
                for (int off = 32; off; off >>= 1)
                    part[e] += __shfl_xor(part[e], off, 64);
            if (lane == 0) {
                float m = part[0];
#pragma unroll
                for (int e = 1; e < NEXP; ++e) m = fmaxf(m, part[e]);
                float p[NEXP], s = 0.f;
#pragma unroll
                for (int e = 0; e < NEXP; ++e) { p[e] = expf(part[e] - m); s += p[e]; }
                float inv = 1.f / s;
#pragma unroll
                for (int e = 0; e < NEXP; ++e) {
                    p[e] *= inv;
                    probs_out[(size_t)token * NEXP + e] = p[e];
                }
                int i0 = 0;
#pragma unroll
                for (int e = 1; e < NEXP; ++e) if (p[e] > p[i0]) i0 = e;  // ties -> lowest
                int i1 = (i0 == 0) ? 1 : 0;
#pragma unroll
                for (int e = 0; e < NEXP; ++e) if (e != i0 && p[e] > p[i1]) i1 = e;
                float s2 = 1.f / (p[i0] + p[i1]);
                tok_top[token] = make_int2(i0, i1);
                tok_w[token]   = make_float2(p[i0] * s2, p[i1] * s2);
                atomicAdd(&hist[i0], 1);      // LDS-scope only
                atomicAdd(&hist[i1], 1);
            }
        }
        __syncthreads();
        if (t < NEXP) hist_arr[blk * NEXP + t] = hist[t];   // non-atomic
    } else if (blk < 8448) {
        // ---- convw: fp32 W1+W2 -> bf16 in MFMA-fragment chunk order -------
        // Chunk C = ((e*64 + ng)*32 + kc): lane l holds
        // W[e][ng*16 + (l&15)][kc*32 + (l>>4)*8 .. +7].
        size_t tt = (size_t)(blk - 256) * 256 + t;
        const size_t PER = (size_t)NEXP * HD * HD / 8;
        const float* src = W1; short* dst = D1;
        if (tt >= PER) { tt -= PER; src = W2; dst = D2; }
        size_t C = tt >> 6;
        int l  = (int)(tt & 63);
        int kc = (int)(C & 31);
        int ng = (int)((C >> 5) & 63);
        int ei = (int)(C >> 11);
        int n = ng * 16 + (l & 15);
        int k = kc * 32 + (l >> 4) * 8;
        const float* s = src + ((size_t)ei * HD + n) * HD + k;
        vfloat4 a = *(const vfloat4*)s;
        vfloat4 b = *(const vfloat4*)(s + 4);
        vshort8 o;
        o[0] = bf16r(a.x); o[1] = bf16r(a.y); o[2] = bf16r(a.z); o[3] = bf16r(a.w);
        o[4] = bf16r(b.x); o[5] = bf16r(b.y); o[6] = bf16r(b.z); o[7] = bf16r(b.w);
        *(vshort8*)(dst + tt * 8) = o;
    } else {
        // ---- init: pair_token -> ZROW sentinel, zero ZROW row (ONLY) ------
        int i = (blk - 8448) * 256 + t;
        if (i < MAXP) pair_token[i] = ZROW;
        if (i < HD / 8) {
            vshort8 z = {0, 0, 0, 0, 0, 0, 0, 0};
            *(vshort8*)(xb + (size_t)ZROW * HD + i * 8) = z;
        }
    }
}

// --- K2: deterministic scatter (no device atomics, no pre-zeroed state) ----
// Scatter block b owns tokens [b*256, b*256+256) = ROUTER blocks
// [8b, 8b+8). Slot of a token in expert e = padded_base[e] +
// (sum of hist_arr[rb][e] for rb < 8b) + intra-block rank (LDS atomic).
// Prefix/total via wave shuffle reduce over the 256 histogram rows.
// Block 0 also publishes counts[] for the GEMM's padded prefix.
__global__ __launch_bounds__(256) void scatter_kernel(
    const int2* __restrict__ tok_top, const float2* __restrict__ tok_w,
    const int* __restrict__ hist_arr, int* __restrict__ counts,
    int* __restrict__ pair_token, float* __restrict__ pair_w) {
    __shared__ int lhist[NEXP];
    __shared__ int ppre[4][NEXP];
    __shared__ int ptot[4][NEXP];
    __shared__ int pre[NEXP], tot[NEXP];
    const int t = threadIdx.x, b = blockIdx.x;
    const int wave = t >> 6, lane = t & 63;
    if (t < NEXP) lhist[t] = 0;

    int h[NEXP];
#pragma unroll
    for (int e = 0; e < NEXP; ++e) h[e] = hist_arr[t * NEXP + e];  // row t = router block t
#pragma unroll
    for (int e = 0; e < NEXP; ++e) {
        int vp = (t < b * 8) ? h[e] : 0;    // router blocks BEFORE this scatter block
        int vt = h[e];
#pragma unroll
        for (int off = 32; off; off >>= 1) {
            vp += __shfl_xor(vp, off, 64);
            vt += __shfl_xor(vt, off, 64);
        }
        if (lane == 0) { ppre[wave][e] = vp; ptot[wave][e] = vt; }
    }
    __syncthreads();
    if (t < NEXP) {
        int p = 0, s = 0;
#pragma unroll
        for (int w = 0; w < 4; ++w) { p += ppre[w][t]; s += ptot[w][t]; }
        pre[t] = p; tot[t] = s;
        if (b == 0) counts[t] = s;          // consumed by later GEMM dispatches
    }
    __syncthreads();
    int base[NEXP];
    {
        int acc = 0;
#pragma unroll
        for (int f = 0; f < NEXP; ++f) { base[f] = acc; acc += (tot[f] + 127) & ~127; }
    }
    int token = b * 256 + t;
    int2 ti = tok_top[token];
    float2 tw = tok_w[token];
    int r0 = atomicAdd(&lhist[ti.x], 1);    // LDS-scope only
    int r1 = atomicAdd(&lhist[ti.y], 1);
    int s0 = base[ti.x] + pre[ti.x] + r0;
    pair_token[s0] = token; pair_w[s0] = tw.x;
    int s1 = base[ti.y] + pre[ti.y] + r1;
    pair_token[s1] = token; pair_w[s1] = tw.y;
}

// --- K3/K4: grouped NT-GEMM (R5 verbatim, natural block mapping) -----------
// row_t = blockIdx.x, col_t = blockIdx.y (measured-best: XCD = row_t%8 ->
// per-XCD A slice 2.2MB L2-resident). 8 waves (2x4) of 64x32; 64KB LDS dbuf;
// per k-step: STAGE next (2 gld_lds/wave), counted vmcnt(4), s_barrier,
// 12 ds_read_b128 + 16 MFMA, s_barrier.
// MODE 0: A rows via pair_token; epi relu(acc+b1)->LDS->chunk-ordered h1.
// MODE 1: A = chunk-ordered h1; epi atomicAdd out += w*(acc+b2).
template <int MODE>
__global__ __launch_bounds__(512, 4) void moe_gemm(
    const short* __restrict__ A, const short* __restrict__ Bw,
    const float* __restrict__ bias, const int* __restrict__ pair_token,
    const float* __restrict__ pair_w, const int* __restrict__ counts,
    short* __restrict__ h1sw_out, float* __restrict__ out) {
    __shared__ short smem[32768];   // 64 KB: A dbuf [0..16383], B dbuf [16384..32767]

    const int row0 = blockIdx.x * BM;
    // inline padded prefix over counts -> expert id + total
    int e = 0;
    {
        int csum = 0;
#pragma unroll
        for (int f = 0; f < NEXP; ++f) {
            int p = (counts[f] + 127) & ~127;
            if (csum + p <= row0) e = f + 1;
            csum += p;
        }
        if (row0 >= csum) return;       // past padded total
    }

    const int t = threadIdx.x;
    const int wave = t >> 6, lane = t & 63;
    const int wm = wave >> 2, wn = wave & 3;
    const int quad = lane >> 4, l16 = lane & 15;
    const int colb = blockIdx.y * BN;

    // per-lane global source pointers (at k0 = 0)
    const char* agp;
    if (MODE == 0) {
        int tok = pair_token[row0 + wave * 16 + l16];
        agp = (const char*)A + (size_t)tok * (HD * 2) + quad * 16;
    } else {
        agp = (const char*)A + (((size_t)(row0 >> 4) + wave) * 32) * 1024 + lane * 16;
    }
    const char* bgp = (const char*)Bw +
        (((size_t)e * 64 + (colb >> 4) + wave) * 32) * 1024 + lane * 16;

    vfloat4 acc[4][2];
#pragma unroll
    for (int i = 0; i < 4; ++i)
#pragma unroll
        for (int j = 0; j < 2; ++j)
            acc[i][j] = (vfloat4){0.f, 0.f, 0.f, 0.f};

#define STAGE(bsel, kk0)                                                      \
    {                                                                         \
        const int kc_ = (kk0) >> 5;                                           \
        short* sa_ = smem + (bsel) * 8192;                                    \
        short* sb_ = smem + 16384 + (bsel) * 8192;                            \
        _Pragma("unroll")                                                     \
        for (int s = 0; s < 2; ++s) {                                         \
            const char* ga_ = (MODE == 0)                                     \
                ? (agp + (size_t)(kk0) * 2 + s * 64)                          \
                : (agp + (size_t)(kc_ + s) * 1024);                           \
            gld16(ga_, sa_ + (wave * 2 + s) * 512);                           \
            gld16(bgp + (size_t)(kc_ + s) * 1024, sb_ + (wave * 2 + s) * 512);\
        }                                                                     \
    }

    STAGE(0, 0)                              // prologue: 4 loads in flight
    int cur = 0;
    for (int kt = 0; kt < HD / BK; ++kt) {
        if (kt < HD / BK - 1) {
            STAGE(cur ^ 1, (kt + 1) * BK)    // issue next tile: 8 outstanding
            asm volatile("s_waitcnt vmcnt(4)" ::: "memory");  // step-kt loads landed
        } else {
            asm volatile("s_waitcnt vmcnt(0)" ::: "memory");  // drain last tile
        }
        __builtin_amdgcn_s_barrier();        // all waves' tile kt in LDS
        asm volatile("" ::: "memory");
        const short* sa = smem + cur * 8192;
        const short* sb = smem + 16384 + cur * 8192;
#pragma unroll
        for (int s = 0; s < 2; ++s) {
            vshort8 af[4], bfr[2];
#pragma unroll
            for (int i = 0; i < 4; ++i)
                af[i] = *(const vshort8*)(sa + ((wm * 4 + i) * 2 + s) * 512 + lane * 8);
#pragma unroll
            for (int j = 0; j < 2; ++j)
                bfr[j] = *(const vshort8*)(sb + ((wn * 2 + j) * 2 + s) * 512 + lane * 8);
#pragma unroll
            for (int i = 0; i < 4; ++i)
#pragma unroll
                for (int j = 0; j < 2; ++j)
                    acc[i][j] = __builtin_amdgcn_mfma_f32_16x16x32_bf16(af[i], bfr[j], acc[i][j], 0, 0, 0);
        }
        asm volatile("" ::: "memory");
        __builtin_amdgcn_s_barrier();        // reads of buf[cur] done before restage
        cur ^= 1;
    }
#undef STAGE

    if (MODE == 0) {
        // epilogue: relu(acc+b1) -> bf16 LDS tile -> chunk-ordered h1sw
        __syncthreads();
#pragma unroll
        for (int j = 0; j < 2; ++j) {
            int col = wn * 32 + j * 16 + l16;
            float bv = bias[e * HD + colb + col];
#pragma unroll
            for (int i = 0; i < 4; ++i) {
                int rl = wm * 64 + i * 16 + quad * 4;
#pragma unroll
                for (int reg = 0; reg < 4; ++reg) {
                    float v = acc[i][j][reg] + bv;
                    v = v > 0.f ? v : 0.f;
                    smem[(rl + reg) * EP_LDSW + col] = bf16r(v);
                }
            }
        }
        __syncthreads();
        int lrow = wave * 16 + l16;
#pragma unroll
        for (int kk = 0; kk < 4; ++kk) {
            vshort8 v = *(const vshort8*)(smem + lrow * EP_LDSW + kk * 32 + quad * 8);
            size_t chunk = ((size_t)(row0 >> 4) + wave) * 32 + (colb >> 5) + kk;
            *(vshort8*)(h1sw_out + chunk * 512 + lane * 8) = v;
        }
    } else {
        int tok[4][4]; float wv[4][4];
#pragma unroll
        for (int i = 0; i < 4; ++i)
#pragma unroll
            for (int reg = 0; reg < 4; ++reg) {
                int r = row0 + wm * 64 + i * 16 + quad * 4 + reg;
                tok[i][reg] = pair_token[r];
                wv[i][reg] = pair_w[r];
            }
#pragma unroll
        for (int j = 0; j < 2; ++j) {
            int col = colb + wn * 32 + j * 16 + l16;
            float bv = bias[e * HD + col];
#pragma unroll
            for (int i = 0; i < 4; ++i)
#pragma unroll
                for (int reg = 0; reg < 4; ++reg)
                    if (tok[i][reg] < ZROW)
                        atomicAdd(out + (size_t)tok[i][reg] * HD + col,
                                  wv[i][reg] * (acc[i][j][reg] + bv));
        }
    }
}

extern "C" void kernel_launch(void* const* d_in, const int* in_sizes, int n_in,
                              void* d_out, int out_size, void* d_ws, size_t ws_size,
                              hipStream_t stream) {
    const float* x  = (const float*)d_in[0];
    const float* rw = (const float*)d_in[1];
    const float* W1 = (const float*)d_in[2];
    const float* b1 = (const float*)d_in[3];
    const float* W2 = (const float*)d_in[4];
    const float* b2 = (const float*)d_in[5];
    float* out   = (float*)d_out;                // [8192,1024] residual+moe
    float* probs = out + (size_t)NTOK * HD;      // [8192,8]

    char* ws = (char*)d_ws;
    short* xb = (short*)ws;            ws += (size_t)(NTOK + 1) * HD * 2;
    short* h1 = (short*)ws;            ws += (size_t)MAXP * HD * 2;
    int*   pair_token = (int*)ws;      ws += MAXP * 4;
    float* pair_w     = (float*)ws;    ws += MAXP * 4;
    int*   counts   = (int*)ws;        ws += 256;
    int*   hist_arr = (int*)ws;        ws += 256 * NEXP * 4;
    int2*   tok_top = (int2*)ws;       ws += NTOK * 8;
    float2* tok_w   = (float2*)ws;     ws += NTOK * 8;
    short* w1sw = (short*)ws;          ws += (size_t)NEXP * HD * HD * 2;
    short* w2sw = (short*)ws;          ws += (size_t)NEXP * HD * HD * 2;
    (void)ws_size;

    // prep: router [0,256) | convw [256,8448) | init [8448,8516)
    prep_kernel<<<8516, 256, 0, stream>>>(x, rw, out, xb, probs, tok_top, tok_w,
                                          hist_arr, pair_token,
                                          W1, W2, w1sw, w2sw);
    scatter_kernel<<<NTOK / 256, 256, 0, stream>>>(tok_top, tok_w, hist_arr,
                                                   counts, pair_token, pair_w);
    dim3 gg(136, 8);                   // natural mapping; past-total exit
    moe_gemm<0><<<gg, 512, 0, stream>>>(xb, w1sw, b1, pair_token, pair_w, counts, h1, nullptr);
    moe_gemm<1><<<gg, 512, 0, stream>>>(h1, w2sw, b2, pair_token, pair_w, counts, nullptr, out);
}